// Round 4
// baseline (281.023 us; speedup 1.0000x reference)
//
#include <hip/hip_runtime.h>
#include <math.h>

#define B_SZ 24
#define D_EMBD 512
#define N_CLS 10000
#define CC 256
#define HH 196

#define S_SCALE 64.0f
#define COS_M 0.9004471023526769f
#define SIN_M 0.43496553411123023f
#define TH_C (-0.9004471023526769f)
#define MM_C 0.19573449035005357f
#define KSC 14.4269504088896f          /* 10*log2(e) */
#define C2E 0.0693147180559945f        /* eps*ln2 */

typedef short bfrag8 __attribute__((ext_vector_type(8)));
typedef float facc4 __attribute__((ext_vector_type(4)));

#if __has_builtin(__builtin_amdgcn_exp2f)
#define EXP2F(x) __builtin_amdgcn_exp2f(x)
#else
#define EXP2F(x) exp2f(x)
#endif
#if __has_builtin(__builtin_amdgcn_logf)
#define LOG2F(x) __builtin_amdgcn_logf(x)
#else
#define LOG2F(x) __log2f(x)
#endif

__device__ inline unsigned short f2bf_rne(float x) {
    union { float f; unsigned u; } cv; cv.f = x;
    unsigned r = cv.u + 0x7FFFu + ((cv.u >> 16) & 1u);
    return (unsigned short)(r >> 16);
}
__device__ inline float bf2f(unsigned short h) {
    union { unsigned u; float f; } cv; cv.u = ((unsigned)h) << 16; return cv.f;
}
__device__ inline float bflo(unsigned u) {
    union { unsigned x; float f; } c; c.x = u << 16; return c.f;
}
__device__ inline float bfhi(unsigned u) {
    union { unsigned x; float f; } c; c.x = u & 0xffff0000u; return c.f;
}

// ============ Launch 1: k_gemmE ============
// bid < 552: half-pair GEMM. pairIdx = bid>>1, half = bid&1: rows half*128..+128 of pair (a,b).
//   Computes Ceps2 for 128x256, row-mins, writes E = 2^(rm - Ceps2) packed bf16 to E16 (sink layout),
//   rm fp32 to rm_ws.
// bid >= 552: 24x24 emb-cosine gram (8 pairs/block). Block 552 zeros Dmat diag.
__global__ __launch_bounds__(512, 2) void k_gemmE(const float* __restrict__ emb,
        const float* __restrict__ conv, float* __restrict__ dists,
        float* __restrict__ Dmat, float* __restrict__ rm_ws,
        unsigned short* __restrict__ E16) {
    const int t = threadIdx.x;
    const int bid = blockIdx.x;

    if (bid >= 552) {
        int l = t & 63, w16 = t >> 6;
        if (bid == 552 && t < B_SZ) Dmat[t * B_SZ + t] = 0.f;
        int pid = (bid - 552) * 8 + w16;
        if (pid >= B_SZ * B_SZ) return;
        int i = pid / B_SZ, j = pid - (pid / B_SZ) * B_SZ;
        float sij = 0.f, sii = 0.f, sjj = 0.f;
        #pragma unroll
        for (int u = 0; u < 8; ++u) {
            float vi = emb[i*D_EMBD + u*64 + l];
            float vj = emb[j*D_EMBD + u*64 + l];
            sij = fmaf(vi, vj, sij); sii = fmaf(vi, vi, sii); sjj = fmaf(vj, vj, sjj);
        }
        #pragma unroll
        for (int o = 1; o < 64; o <<= 1) {
            sij += __shfl_xor(sij, o, 64);
            sii += __shfl_xor(sii, o, 64);
            sjj += __shfl_xor(sjj, o, 64);
        }
        if (l == 0) dists[pid] = sij * rsqrtf(sii * sjj);
        return;
    }

    __shared__ __align__(16) unsigned short AhS[128*32];   // 8 KB
    __shared__ __align__(16) unsigned short AlS[128*32];
    __shared__ __align__(16) unsigned short BhS[256*32];   // 16 KB
    __shared__ __align__(16) unsigned short BlS[256*32];
    __shared__ float na_s[128], nb_s[256];
    __shared__ float rowred[4*128];
    __shared__ float rm_l[128];

    const int pair = bid >> 1, half = bid & 1;
    int rem = pair, a = 0;
    while (rem >= 23 - a) { rem -= 23 - a; ++a; }
    int b = a + 1 + rem;
    const float* xa = conv + a*CC*HH + half*128*HH;   // 128 rows
    const float* xb = conv + b*CC*HH;                 // 256 rows

    const int w = t >> 6;                 // 0..7
    const int wrg = w >> 2, wcg = w & 3;  // 2 x 4 wave grid (64-row x 64-col tiles)
    const int q = (t >> 4) & 3, c0 = t & 15;
    const int R0l = wrg * 64, C0 = wcg * 64;

    const int snA = t >> 2, schA = t & 3;   // A: 128 rows x 4 chunks of 8
    const int snB = t >> 1, khB = t & 1;    // B: 256 rows x 2 halves of 16

    facc4 acc[4][4];
    #pragma unroll
    for (int i = 0; i < 4; ++i)
        #pragma unroll
        for (int j = 0; j < 4; ++j) acc[i][j] = (facc4){0.f, 0.f, 0.f, 0.f};

    float pa = 0.f, pb = 0.f;

    for (int ks = 0; ks < 224; ks += 32) {
        __syncthreads();
        {   // A staging: 8 el
            int k0 = ks + schA*8;
            const float* src = xa + snA*HH + k0;
            float v[8];
            if (k0 + 8 <= HH) {
                const float4* s4 = (const float4*)src;
                float4 u0 = s4[0], u1 = s4[1];
                v[0]=u0.x; v[1]=u0.y; v[2]=u0.z; v[3]=u0.w;
                v[4]=u1.x; v[5]=u1.y; v[6]=u1.z; v[7]=u1.w;
            } else {
                #pragma unroll
                for (int j = 0; j < 8; ++j) v[j] = (k0 + j < HH) ? src[j] : 0.f;
            }
            float ps = 0.f;
            union { unsigned short s[8]; bfrag8 v8; } uh, ul;
            #pragma unroll
            for (int j = 0; j < 8; ++j) {
                ps = fmaf(v[j], v[j], ps);
                unsigned short hb = f2bf_rne(v[j]);
                uh.s[j] = hb;
                ul.s[j] = f2bf_rne(v[j] - bf2f(hb));
            }
            pa += ps;
            *(bfrag8*)&AhS[snA*32 + schA*8] = uh.v8;
            *(bfrag8*)&AlS[snA*32 + schA*8] = ul.v8;
        }
        {   // B staging: 16 el
            int k0 = ks + khB*16;
            const float* src = xb + snB*HH + k0;
            float v[16];
            if (k0 + 16 <= HH) {
                const float4* s4 = (const float4*)src;
                #pragma unroll
                for (int p4 = 0; p4 < 4; ++p4) {
                    float4 u = s4[p4];
                    v[p4*4+0]=u.x; v[p4*4+1]=u.y; v[p4*4+2]=u.z; v[p4*4+3]=u.w;
                }
            } else {
                #pragma unroll
                for (int j = 0; j < 16; ++j) v[j] = (k0 + j < HH) ? src[j] : 0.f;
            }
            float ps = 0.f;
            union { unsigned short s[16]; bfrag8 v8[2]; } uh, ul;
            #pragma unroll
            for (int j = 0; j < 16; ++j) {
                ps = fmaf(v[j], v[j], ps);
                unsigned short hb = f2bf_rne(v[j]);
                uh.s[j] = hb;
                ul.s[j] = f2bf_rne(v[j] - bf2f(hb));
            }
            pb += ps;
            *(bfrag8*)&BhS[snB*32 + khB*16] = uh.v8[0];
            *(bfrag8*)&BhS[snB*32 + khB*16 + 8] = uh.v8[1];
            *(bfrag8*)&BlS[snB*32 + khB*16] = ul.v8[0];
            *(bfrag8*)&BlS[snB*32 + khB*16 + 8] = ul.v8[1];
        }
        __syncthreads();
        bfrag8 bh4[4], bl4[4];
        #pragma unroll
        for (int tj = 0; tj < 4; ++tj) {
            int col = C0 + tj*16 + c0;
            bh4[tj] = *(const bfrag8*)&BhS[col*32 + q*8];
            bl4[tj] = *(const bfrag8*)&BlS[col*32 + q*8];
        }
        #pragma unroll
        for (int ti = 0; ti < 4; ++ti) {
            int row = R0l + ti*16 + c0;
            bfrag8 ah = *(const bfrag8*)&AhS[row*32 + q*8];
            bfrag8 al = *(const bfrag8*)&AlS[row*32 + q*8];
            #pragma unroll
            for (int tj = 0; tj < 4; ++tj) {
                acc[ti][tj] = __builtin_amdgcn_mfma_f32_16x16x32_bf16(ah, bh4[tj], acc[ti][tj], 0, 0, 0);
                acc[ti][tj] = __builtin_amdgcn_mfma_f32_16x16x32_bf16(ah, bl4[tj], acc[ti][tj], 0, 0, 0);
                acc[ti][tj] = __builtin_amdgcn_mfma_f32_16x16x32_bf16(al, bh4[tj], acc[ti][tj], 0, 0, 0);
            }
        }
    }

    // point norms
    pa += __shfl_xor(pa, 1, 64); pa += __shfl_xor(pa, 2, 64);
    pb += __shfl_xor(pb, 1, 64);
    if (schA == 0) na_s[snA] = pa;
    if (khB == 0) nb_s[snB] = pb;
    __syncthreads();

    // Ceps2 (C/D layout: row = R0l + ti*16 + q*4 + r, col = C0 + tj*16 + c0)
    facc4 Cv[4][4];
    {
        float nbv[4];
        #pragma unroll
        for (int tj = 0; tj < 4; ++tj) nbv[tj] = nb_s[C0 + tj*16 + c0];
        #pragma unroll
        for (int ti = 0; ti < 4; ++ti) {
            facc4 nav = *(const facc4*)&na_s[R0l + ti*16 + q*4];
            #pragma unroll
            for (int tj = 0; tj < 4; ++tj) {
                #pragma unroll
                for (int r = 0; r < 4; ++r) {
                    float d2 = fmaxf(nav[r] + nbv[tj] - 2.f*acc[ti][tj][r], 0.f);
                    Cv[ti][tj][r] = KSC * sqrtf(d2 + 1e-12f);
                }
            }
        }
    }

    const int istar = ((c0&1)<<3) | ((c0&2)<<1) | ((c0&4)>>1) | ((c0&8)>>3);
    const int rowstar = R0l + (istar>>2)*16 + q*4 + (istar&3);

    // row mins over 256 cols
    {
        float v16[16];
        #pragma unroll
        for (int ti = 0; ti < 4; ++ti)
            #pragma unroll
            for (int r = 0; r < 4; ++r)
                v16[ti*4+r] = fminf(fminf(Cv[ti][0][r], Cv[ti][1][r]),
                                    fminf(Cv[ti][2][r], Cv[ti][3][r]));
        #pragma unroll
        for (int p = 0; p < 4; ++p) {
            const int m = 1 << p, hsz = 8 >> p;
            const bool hi = (c0 >> p) & 1;
            #pragma unroll
            for (int j = 0; j < hsz; ++j) {
                float mine = hi ? v16[j+hsz] : v16[j];
                float send = hi ? v16[j] : v16[j+hsz];
                v16[j] = fminf(mine, __shfl_xor(send, m, 64));
            }
        }
        rowred[wcg*128 + rowstar] = v16[0];
    }
    __syncthreads();
    if (t < 128) {
        float m = fminf(fminf(rowred[t], rowred[128+t]), fminf(rowred[256+t], rowred[384+t]));
        rm_l[t] = m;
        rm_ws[pair*256 + half*128 + t] = m;
    }
    __syncthreads();

    // E = 2^(rm - Ceps2) -> bf16 packed, stored in sink-thread layout:
    // s = ((half*2+wrg)*2 + (wcg>>1))*64 + q*16 + c0 ; j = ti*32 + ((wcg&1)*4+tj)*4 + r
    {
        const int s = ((half*2 + wrg)*2 + (wcg>>1))*64 + q*16 + c0;
        unsigned short* Ep = E16 + (size_t)pair*65536 + s*128;
        #pragma unroll
        for (int ti = 0; ti < 4; ++ti) {
            facc4 rmv = *(const facc4*)&rm_l[R0l + ti*16 + q*4];
            #pragma unroll
            for (int tj = 0; tj < 4; ++tj) {
                float e0 = EXP2F(rmv[0] - Cv[ti][tj][0]);
                float e1 = EXP2F(rmv[1] - Cv[ti][tj][1]);
                float e2 = EXP2F(rmv[2] - Cv[ti][tj][2]);
                float e3 = EXP2F(rmv[3] - Cv[ti][tj][3]);
                unsigned lo = (unsigned)f2bf_rne(e0) | ((unsigned)f2bf_rne(e1) << 16);
                unsigned hi = (unsigned)f2bf_rne(e2) | ((unsigned)f2bf_rne(e3) << 16);
                uint2 pk; pk.x = lo; pk.y = hi;
                int j0 = ti*32 + ((wcg&1)*4 + tj)*4;
                *(uint2*)&Ep[j0] = pk;
            }
        }
    }
}

// ============ Launch 2: k_sink ============
// 276 blocks x 512 thr, E packed bf16 in 64 VGPRs. Wave grid 4x2 (wr x wc):
// thread owns rows R0+ti*16+q*4+r (ti<4,r<4), cols C0+tj*16+c0 (tj<8).
__global__ __launch_bounds__(512, 4) void k_sink(const unsigned short* __restrict__ E16,
        const float* __restrict__ rm_ws, float* __restrict__ Dmat) {
    __shared__ float rowred[2*256];
    __shared__ float colred[4*256];
    __shared__ float z_l[256], g_l[256], rm_l[256];
    __shared__ float wredF[4], wredG[4], wredD[8];

    const int t = threadIdx.x;
    const int w = t >> 6;
    const int wr = w >> 1, wc = w & 1;
    const int q = (t >> 4) & 3, c0 = t & 15;
    const int R0 = wr * 64, C0 = wc * 128;
    const int pair = blockIdx.x;

    int rem = pair, a = 0;
    while (rem >= 23 - a) { rem -= 23 - a; ++a; }
    int b = a + 1 + rem;

    // load E: 64 packed u32 (contiguous 256B per thread)
    unsigned ue[64];
    {
        const uint4* eb = (const uint4*)(E16 + (size_t)pair*65536 + t*128);
        #pragma unroll
        for (int i = 0; i < 16; ++i) {
            uint4 v = eb[i];
            ue[i*4+0] = v.x; ue[i*4+1] = v.y; ue[i*4+2] = v.z; ue[i*4+3] = v.w;
        }
    }
    if (t < 256) { rm_l[t] = rm_ws[pair*256 + t]; g_l[t] = 0.f; }
    if (t < 4) wredG[t] = 0.f;
    __syncthreads();

    const int istar = ((c0&1)<<3) | ((c0&2)<<1) | ((c0&4)>>1) | ((c0&8)>>3);
    const int rowstar = R0 + (istar>>2)*16 + q*4 + (istar&3);

    #pragma unroll 1
    for (int it = 0; it < 6; ++it) {
        // phase A: row partials S_r = sum_tj E * P
        float Gmax = fmaxf(fmaxf(wredG[0], wredG[1]), fmaxf(wredG[2], wredG[3]));
        float P8[8];
        #pragma unroll
        for (int tj = 0; tj < 8; ++tj) P8[tj] = EXP2F(g_l[C0 + tj*16 + c0] - Gmax);
        float v16[16];
        #pragma unroll
        for (int ti = 0; ti < 4; ++ti) {
            float s0 = 0.f, s1 = 0.f, s2 = 0.f, s3 = 0.f;
            #pragma unroll
            for (int tj = 0; tj < 8; ++tj) {
                unsigned u0 = ue[(ti*8+tj)*2], u1 = ue[(ti*8+tj)*2+1];
                float p = P8[tj];
                s0 = fmaf(bflo(u0), p, s0); s1 = fmaf(bfhi(u0), p, s1);
                s2 = fmaf(bflo(u1), p, s2); s3 = fmaf(bfhi(u1), p, s3);
            }
            v16[ti*4+0]=s0; v16[ti*4+1]=s1; v16[ti*4+2]=s2; v16[ti*4+3]=s3;
        }
        #pragma unroll
        for (int p = 0; p < 4; ++p) {
            const int m = 1 << p, hsz = 8 >> p;
            const bool hi = (c0 >> p) & 1;
            #pragma unroll
            for (int j = 0; j < hsz; ++j) {
                float mine = hi ? v16[j+hsz] : v16[j];
                float send = hi ? v16[j] : v16[j+hsz];
                v16[j] = mine + __shfl_xor(send, m, 64);
            }
        }
        rowred[wc*256 + rowstar] = v16[0];
        __syncthreads();
        // phase B: z_r = 8 - Gmax - log2(S_r)
        if (t < 256) {
            float s = rowred[t] + rowred[256+t];
            float z = 8.f - Gmax - LOG2F(s);
            z_l[t] = z;
            float m = z;
            #pragma unroll
            for (int o = 1; o < 64; o <<= 1) m = fmaxf(m, __shfl_xor(m, o, 64));
            if ((t & 63) == 0) wredF[t >> 6] = m;
        }
        __syncthreads();
        // phase C: col partials S_c = sum_rows E * Q
        float M = fmaxf(fmaxf(wredF[0], wredF[1]), fmaxf(wredF[2], wredF[3]));
        float Q[16];
        #pragma unroll
        for (int ti = 0; ti < 4; ++ti) {
            facc4 zv = *(const facc4*)&z_l[R0 + ti*16 + q*4];
            #pragma unroll
            for (int r = 0; r < 4; ++r) Q[ti*4+r] = EXP2F(zv[r] - M);
        }
        float w8[8];
        #pragma unroll
        for (int tj = 0; tj < 8; ++tj) {
            float s = 0.f;
            #pragma unroll
            for (int ti = 0; ti < 4; ++ti) {
                unsigned u0 = ue[(ti*8+tj)*2], u1 = ue[(ti*8+tj)*2+1];
                s = fmaf(bflo(u0), Q[ti*4+0], s); s = fmaf(bfhi(u0), Q[ti*4+1], s);
                s = fmaf(bflo(u1), Q[ti*4+2], s); s = fmaf(bfhi(u1), Q[ti*4+3], s);
            }
            w8[tj] = s;
        }
        // q-tournament over 8 tj (strides 16, 32): lane q ends with tj* = (q&1)*4 + (q>>1)*2 + {0,1}
        {
            #pragma unroll
            for (int p = 0; p < 2; ++p) {
                const int m = 16 << p, hsz = 4 >> p;
                const bool hi = p == 0 ? (q & 1) : ((q >> 1) & 1);
                #pragma unroll
                for (int j = 0; j < hsz; ++j) {
                    float mine = hi ? w8[j+hsz] : w8[j];
                    float send = hi ? w8[j] : w8[j+hsz];
                    w8[j] = mine + __shfl_xor(send, m, 64);
                }
            }
            int tjb = (q&1)*4 + (q>>1)*2;
            colred[wr*256 + C0 + (tjb+0)*16 + c0] = w8[0];
            colred[wr*256 + C0 + (tjb+1)*16 + c0] = w8[1];
        }
        __syncthreads();
        // phase D: G_c = 8 - M - log2(S_c)
        if (t < 256) {
            float s = colred[t] + colred[256+t] + colred[512+t] + colred[768+t];
            float G = 8.f - M - LOG2F(s);
            g_l[t] = G;
            float m = G;
            #pragma unroll
            for (int o = 1; o < 64; o <<= 1) m = fmaxf(m, __shfl_xor(m, o, 64));
            if ((t & 63) == 0) wredG[t >> 6] = m;
        }
        __syncthreads();
    }

    // D = sum(T*C): T = 2^(z_r + G_c - 16 + log2 E), Ceps2 = rm_r - log2 E
    {
        float G8[8];
        #pragma unroll
        for (int tj = 0; tj < 8; ++tj) G8[tj] = g_l[C0 + tj*16 + c0] - 16.f;
        float d = 0.f;
        #pragma unroll
        for (int ti = 0; ti < 4; ++ti) {
            facc4 zv = *(const facc4*)&z_l[R0 + ti*16 + q*4];
            facc4 rmv = *(const facc4*)&rm_l[R0 + ti*16 + q*4];
            #pragma unroll
            for (int tj = 0; tj < 8; ++tj) {
                unsigned u0 = ue[(ti*8+tj)*2], u1 = ue[(ti*8+tj)*2+1];
                float gb = G8[tj];
                float e, lE;
                e = fmaxf(bflo(u0), 1e-38f); lE = LOG2F(e);
                d = fmaf(EXP2F(zv[0] + gb + lE), rmv[0] - lE, d);
                e = fmaxf(bfhi(u0), 1e-38f); lE = LOG2F(e);
                d = fmaf(EXP2F(zv[1] + gb + lE), rmv[1] - lE, d);
                e = fmaxf(bflo(u1), 1e-38f); lE = LOG2F(e);
                d = fmaf(EXP2F(zv[2] + gb + lE), rmv[2] - lE, d);
                e = fmaxf(bfhi(u1), 1e-38f); lE = LOG2F(e);
                d = fmaf(EXP2F(zv[3] + gb + lE), rmv[3] - lE, d);
            }
        }
        d *= C2E;
        #pragma unroll
        for (int o = 1; o < 64; o <<= 1) d += __shfl_xor(d, o, 64);
        if ((t & 63) == 0) wredD[w] = d;
        __syncthreads();
        if (t == 0) {
            float s = 0.f;
            #pragma unroll
            for (int i = 0; i < 8; ++i) s += wredD[i];
            Dmat[a*B_SZ + b] = s;
            Dmat[b*B_SZ + a] = s;
        }
    }
}

// ============ Fallback: R3 monolithic pairs kernel (used when ws too small) ============
__global__ __launch_bounds__(1024) void k_pairs_all(const float* __restrict__ emb,
        const float* __restrict__ conv, float* __restrict__ dists,
        float* __restrict__ Dmat) {
    const int t = threadIdx.x;
    const int bid = blockIdx.x;

    if (bid >= 276) {
        int l = t & 63, w16 = t >> 6;
        if (bid == 276 && t < B_SZ) Dmat[t * B_SZ + t] = 0.f;
        int pid = (bid - 276) * 16 + w16;
        if (pid >= B_SZ * B_SZ) return;
        int i = pid / B_SZ, j = pid - (pid / B_SZ) * B_SZ;
        float sij = 0.f, sii = 0.f, sjj = 0.f;
        #pragma unroll
        for (int u = 0; u < 8; ++u) {
            float vi = emb[i*D_EMBD + u*64 + l];
            float vj = emb[j*D_EMBD + u*64 + l];
            sij = fmaf(vi, vj, sij); sii = fmaf(vi, vi, sii); sjj = fmaf(vj, vj, sjj);
        }
        #pragma unroll
        for (int o = 1; o < 64; o <<= 1) {
            sij += __shfl_xor(sij, o, 64);
            sii += __shfl_xor(sii, o, 64);
            sjj += __shfl_xor(sjj, o, 64);
        }
        if (l == 0) dists[pid] = sij * rsqrtf(sii * sjj);
        return;
    }

    __shared__ __align__(16) char smem[65536];
    unsigned short* Ah = (unsigned short*)smem;
    unsigned short* Al = Ah + 8192;
    unsigned short* Bh = Al + 8192;
    unsigned short* Bl = Bh + 8192;
    float* rowred = (float*)smem;
    float* colred = rowred + 1024;
    float* rm_l   = colred + 1024;
    float* z_l    = rm_l + 256;
    float* g_l    = z_l + 256;
    float* na_s   = g_l + 256;
    float* nb_s   = na_s + 256;
    float* wredF  = nb_s + 256;
    float* wredG  = wredF + 4;
    float* wredD  = wredG + 4;

    const int w = t >> 6;
    const int wr = w >> 2, wc = w & 3;
    const int q = (t >> 4) & 3, c0 = t & 15;
    const int R0 = wr * 64, C0 = wc * 64;

    int rem = bid, a = 0;
    while (rem >= 23 - a) { rem -= 23 - a; ++a; }
    int b = a + 1 + rem;
    const float* xa = conv + a*CC*HH;
    const float* xb = conv + b*CC*HH;

    const int sn = t >> 2;
    const int sch = t & 3;

    facc4 acc[4][4];
    #pragma unroll
    for (int i = 0; i < 4; ++i)
        #pragma unroll
        for (int j = 0; j < 4; ++j) acc[i][j] = (facc4){0.f, 0.f, 0.f, 0.f};

    float pa = 0.f, pb = 0.f;

    for (int ks = 0; ks < 224; ks += 32) {
        __syncthreads();
        #pragma unroll
        for (int p = 0; p < 2; ++p) {
            int k0 = ks + sch*8;
            const float* src = (p ? xb : xa) + sn*HH + k0;
            float v[8];
            if (k0 + 8 <= HH) {
                const float4* s4 = (const float4*)src;
                float4 u0 = s4[0], u1 = s4[1];
                v[0]=u0.x; v[1]=u0.y; v[2]=u0.z; v[3]=u0.w;
                v[4]=u1.x; v[5]=u1.y; v[6]=u1.z; v[7]=u1.w;
            } else {
                #pragma unroll
                for (int j = 0; j < 8; ++j) v[j] = (k0 + j < HH) ? src[j] : 0.f;
            }
            float ps = 0.f;
            union { unsigned short s[8]; bfrag8 v8; } uh, ul;
            #pragma unroll
            for (int j = 0; j < 8; ++j) {
                ps = fmaf(v[j], v[j], ps);
                unsigned short hb = f2bf_rne(v[j]);
                uh.s[j] = hb;
                ul.s[j] = f2bf_rne(v[j] - bf2f(hb));
            }
            if (p) pb += ps; else pa += ps;
            unsigned short* dh = (p ? Bh : Ah) + sn*32 + sch*8;
            unsigned short* dl = (p ? Bl : Al) + sn*32 + sch*8;
            *(bfrag8*)dh = uh.v8;
            *(bfrag8*)dl = ul.v8;
        }
        __syncthreads();
        bfrag8 bh4[4], bl4[4];
        #pragma unroll
        for (int tj = 0; tj < 4; ++tj) {
            int col = C0 + tj*16 + c0;
            bh4[tj] = *(const bfrag8*)(Bh + col*32 + q*8);
            bl4[tj] = *(const bfrag8*)(Bl + col*32 + q*8);
        }
        #pragma unroll
        for (int ti = 0; ti < 4; ++ti) {
            int row = R0 + ti*16 + c0;
            bfrag8 ah = *(const bfrag8*)(Ah + row*32 + q*8);
            bfrag8 al = *(const bfrag8*)(Al + row*32 + q*8);
            #pragma unroll
            for (int tj = 0; tj < 4; ++tj) {
                acc[ti][tj] = __builtin_amdgcn_mfma_f32_16x16x32_bf16(ah, bh4[tj], acc[ti][tj], 0, 0, 0);
                acc[ti][tj] = __builtin_amdgcn_mfma_f32_16x16x32_bf16(ah, bl4[tj], acc[ti][tj], 0, 0, 0);
                acc[ti][tj] = __builtin_amdgcn_mfma_f32_16x16x32_bf16(al, bh4[tj], acc[ti][tj], 0, 0, 0);
            }
        }
    }
    __syncthreads();

    pa += __shfl_xor(pa, 1, 64); pa += __shfl_xor(pa, 2, 64);
    pb += __shfl_xor(pb, 1, 64); pb += __shfl_xor(pb, 2, 64);
    if (sch == 0) { na_s[sn] = pa; nb_s[sn] = pb; }
    if (t < 256) g_l[t] = 0.f;
    if (t < 4) wredG[t] = 0.f;
    __syncthreads();

    facc4 E[4][4];
    {
        float nbv[4];
        #pragma unroll
        for (int tj = 0; tj < 4; ++tj) nbv[tj] = nb_s[C0 + tj*16 + c0];
        #pragma unroll
        for (int ti = 0; ti < 4; ++ti) {
            facc4 nav = *(const facc4*)&na_s[R0 + ti*16 + q*4];
            #pragma unroll
            for (int tj = 0; tj < 4; ++tj) {
                #pragma unroll
                for (int r = 0; r < 4; ++r) {
                    float d2 = fmaxf(nav[r] + nbv[tj] - 2.f*acc[ti][tj][r], 0.f);
                    E[ti][tj][r] = KSC * sqrtf(d2 + 1e-12f);
                }
            }
        }
    }

    const int istar = ((c0&1)<<3) | ((c0&2)<<1) | ((c0&4)>>1) | ((c0&8)>>3);
    const int rowstar = R0 + (istar>>2)*16 + q*4 + (istar&3);
    const int tjstar = ((q&1)<<1) | (q>>1);
    const int colstar = C0 + tjstar*16 + c0;

    {
        float v16[16];
        #pragma unroll
        for (int ti = 0; ti < 4; ++ti)
            #pragma unroll
            for (int r = 0; r < 4; ++r)
                v16[ti*4+r] = fminf(fminf(E[ti][0][r], E[ti][1][r]),
                                    fminf(E[ti][2][r], E[ti][3][r]));
        #pragma unroll
        for (int p = 0; p < 4; ++p) {
            const int m = 1 << p, hsz = 8 >> p;
            const bool hi = (c0 >> p) & 1;
            #pragma unroll
            for (int j = 0; j < hsz; ++j) {
                float mine = hi ? v16[j+hsz] : v16[j];
                float send = hi ? v16[j] : v16[j+hsz];
                v16[j] = fminf(mine, __shfl_xor(send, m, 64));
            }
        }
        rowred[wc*256 + rowstar] = v16[0];
    }
    __syncthreads();
    if (t < 256)
        rm_l[t] = fminf(fminf(rowred[t], rowred[256+t]), fminf(rowred[512+t], rowred[768+t]));
    __syncthreads();

    #pragma unroll
    for (int ti = 0; ti < 4; ++ti) {
        facc4 rmv = *(const facc4*)&rm_l[R0 + ti*16 + q*4];
        #pragma unroll
        for (int tj = 0; tj < 4; ++tj)
            #pragma unroll
            for (int r = 0; r < 4; ++r)
                E[ti][tj][r] = EXP2F(rmv[r] - E[ti][tj][r]);
    }

    #pragma unroll 1
    for (int it = 0; it < 6; ++it) {
        float Gmax = fmaxf(fmaxf(wredG[0], wredG[1]), fmaxf(wredG[2], wredG[3]));
        float P4[4];
        #pragma unroll
        for (int tj = 0; tj < 4; ++tj) P4[tj] = EXP2F(g_l[C0 + tj*16 + c0] - Gmax);
        float v16[16];
        #pragma unroll
        for (int ti = 0; ti < 4; ++ti)
            #pragma unroll
            for (int r = 0; r < 4; ++r) {
                float s = 0.f;
                #pragma unroll
                for (int tj = 0; tj < 4; ++tj) s = fmaf(E[ti][tj][r], P4[tj], s);
                v16[ti*4+r] = s;
            }
        #pragma unroll
        for (int p = 0; p < 4; ++p) {
            const int m = 1 << p, hsz = 8 >> p;
            const bool hi = (c0 >> p) & 1;
            #pragma unroll
            for (int j = 0; j < hsz; ++j) {
                float mine = hi ? v16[j+hsz] : v16[j];
                float send = hi ? v16[j] : v16[j+hsz];
                v16[j] = mine + __shfl_xor(send, m, 64);
            }
        }
        rowred[wc*256 + rowstar] = v16[0];
        __syncthreads();
        if (t < 256) {
            float s = rowred[t] + rowred[256+t] + rowred[512+t] + rowred[768+t];
            float z = 8.f - Gmax - LOG2F(s);
            z_l[t] = z;
            float m = z;
            #pragma unroll
            for (int o = 1; o < 64; o <<= 1) m = fmaxf(m, __shfl_xor(m, o, 64));
            if ((t & 63) == 0) wredF[t >> 6] = m;
        }
        __syncthreads();
        float M = fmaxf(fmaxf(wredF[0], wredF[1]), fmaxf(wredF[2], wredF[3]));
        float Q[16];
        #pragma unroll
        for (int ti = 0; ti < 4; ++ti) {
            facc4 zv = *(const facc4*)&z_l[R0 + ti*16 + q*4];
            #pragma unroll
            for (int r = 0; r < 4; ++r) Q[ti*4+r] = EXP2F(zv[r] - M);
        }
        float w4[4];
        #pragma unroll
        for (int tj = 0; tj < 4; ++tj) {
            float s = 0.f;
            #pragma unroll
            for (int ti = 0; ti < 4; ++ti)
                #pragma unroll
                for (int r = 0; r < 4; ++r) s = fmaf(E[ti][tj][r], Q[ti*4+r], s);
            w4[tj] = s;
        }
        #pragma unroll
        for (int p = 0; p < 2; ++p) {
            const int m = 16 << p, hsz = 2 >> p;
            const bool hi = (q >> p) & 1;
            #pragma unroll
            for (int j = 0; j < hsz; ++j) {
                float mine = hi ? w4[j+hsz] : w4[j];
                float send = hi ? w4[j] : w4[j+hsz];
                w4[j] = mine + __shfl_xor(send, m, 64);
            }
        }
        colred[wr*256 + colstar] = w4[0];
        __syncthreads();
        if (t < 256) {
            float s = colred[t] + colred[256+t] + colred[512+t] + colred[768+t];
            float G = 8.f - M - LOG2F(s);
            g_l[t] = G;
            float m = G;
            #pragma unroll
            for (int o = 1; o < 64; o <<= 1) m = fmaxf(m, __shfl_xor(m, o, 64));
            if ((t & 63) == 0) wredG[t >> 6] = m;
        }
        __syncthreads();
    }

    {
        float G4[4];
        #pragma unroll
        for (int tj = 0; tj < 4; ++tj) G4[tj] = g_l[C0 + tj*16 + c0] - 16.f;
        float d = 0.f;
        #pragma unroll
        for (int ti = 0; ti < 4; ++ti) {
            facc4 zv = *(const facc4*)&z_l[R0 + ti*16 + q*4];
            facc4 rmv = *(const facc4*)&rm_l[R0 + ti*16 + q*4];
            #pragma unroll
            for (int tj = 0; tj < 4; ++tj) {
                #pragma unroll
                for (int r = 0; r < 4; ++r) {
                    float e = fmaxf(E[ti][tj][r], 1e-45f);
                    float lE = LOG2F(e);
                    d = fmaf(EXP2F(zv[r] + G4[tj] + lE), rmv[r] - lE, d);
                }
            }
        }
        d *= C2E;
        #pragma unroll
        for (int o = 1; o < 64; o <<= 1) d += __shfl_xor(d, o, 64);
        if ((t & 63) == 0) wredD[w] = d;
        __syncthreads();
        if (t == 0) {
            float s = 0.f;
            #pragma unroll
            for (int i = 0; i < 16; ++i) s += wredD[i];
            Dmat[a*B_SZ + b] = s;
            Dmat[b*B_SZ + a] = s;
        }
    }
}

// ============ Launch 3: arcface (blocks 0..312) + final (block 313) ============
__global__ __launch_bounds__(256) void k_arc_fin(const float* __restrict__ emb,
        const float* __restrict__ kern, const int* __restrict__ label,
        const float* __restrict__ dists, const float* __restrict__ Dmat,
        float* __restrict__ out) {
    const int t = threadIdx.x;
    const int bid = blockIdx.x;

    if (bid == 313) {
        __shared__ float ds[576], Dm[576];
        __shared__ int lab[B_SZ];
        __shared__ float wls[4]; __shared__ int wnp[4], wot[4];
        for (int i = t; i < 576; i += 256) { ds[i] = dists[i]; Dm[i] = Dmat[i]; }
        if (t < B_SZ) lab[t] = label[t];
        __syncthreads();
        int np = 0, ot = 0; float wsum = 0.f;
        for (int idx = t; idx < 24*24*24; idx += 256) {
            int a2 = idx / 576;
            int rest = idx - a2*576;
            int p2 = rest / 24;
            int n2 = rest - p2*24;
            int la = lab[a2];
            if (la == lab[p2] && la != lab[n2]) {
                float diff = ds[a2*24 + n2] - ds[a2*24 + p2];
                if (diff > 0.f) {
                    ++np;
                    float dd = Dm[a2*24 + p2] - Dm[a2*24 + n2];
                    if (dd > 0.f) { ++ot; wsum += dd; }
                }
            }
        }
        #pragma unroll
        for (int o = 1; o < 64; o <<= 1) {
            np += __shfl_xor(np, o, 64);
            ot += __shfl_xor(ot, o, 64);
            wsum += __shfl_xor(wsum, o, 64);
        }
        int w = t >> 6;
        if ((t & 63) == 0) { wnp[w] = np; wot[w] = ot; wls[w] = wsum; }
        __syncthreads();
        if (t == 0) {
            int tnp = wnp[0]+wnp[1]+wnp[2]+wnp[3];
            int tot = wot[0]+wot[1]+wot[2]+wot[3];
            float tws = wls[0]+wls[1]+wls[2]+wls[3];
            int den = tot > 1 ? tot : 1;
            float wl = (tws > 0.f) ? tws / (float)den : 0.f;
            out[240000] = wl;
            out[480001] = (float)tnp;
            out[480002] = (float)tot;
        }
        return;
    }

    __shared__ __align__(16) float es[B_SZ*D_EMBD];
    __shared__ float inv_s[B_SZ];
    __shared__ int lab_s[B_SZ];
    float* part = es;
    float* resb = es + 6400;

    {
        const float4* s4 = (const float4*)emb;
        float4* d4 = (float4*)es;
        for (int i = t; i < (B_SZ*D_EMBD)/4; i += 256) d4[i] = s4[i];
    }
    if (t < B_SZ) lab_s[t] = label[t];
    __syncthreads();
    {
        int l = t & 63, w = t >> 6;
        for (int r = w; r < B_SZ; r += 4) {
            float s = 0.f;
            #pragma unroll
            for (int u = 0; u < 8; ++u) { float v = es[r*D_EMBD + u*64 + l]; s = fmaf(v, v, s); }
            #pragma unroll
            for (int o = 1; o < 64; o <<= 1) s += __shfl_xor(s, o, 64);
            if (l == 0) inv_s[r] = rsqrtf(s);
        }
    }
    __syncthreads();

    const int cc = t & 31, kc = t >> 5;
    int c = bid*32 + cc;
    int cL = c < N_CLS ? c : N_CLS - 1;
    float acc[B_SZ];
    #pragma unroll
    for (int r = 0; r < B_SZ; ++r) acc[r] = 0.f;
    float cn = 0.f;
    const int k0 = kc*64;
    for (int u = 0; u < 16; ++u) {
        int kb = k0 + u*4;
        float kv0 = kern[(kb+0)*N_CLS + cL];
        float kv1 = kern[(kb+1)*N_CLS + cL];
        float kv2 = kern[(kb+2)*N_CLS + cL];
        float kv3 = kern[(kb+3)*N_CLS + cL];
        cn = fmaf(kv0,kv0,cn); cn = fmaf(kv1,kv1,cn);
        cn = fmaf(kv2,kv2,cn); cn = fmaf(kv3,kv3,cn);
        #pragma unroll
        for (int r = 0; r < B_SZ; ++r) {
            const float4 e = *(const float4*)&es[r*D_EMBD + kb];
            acc[r] = fmaf(e.x, kv0, acc[r]);
            acc[r] = fmaf(e.y, kv1, acc[r]);
            acc[r] = fmaf(e.z, kv2, acc[r]);
            acc[r] = fmaf(e.w, kv3, acc[r]);
        }
    }
    __syncthreads();
    #pragma unroll
    for (int r = 0; r < B_SZ; ++r) part[kc*800 + cc*25 + r] = acc[r];
    part[kc*800 + cc*25 + 24] = cn;
    __syncthreads();
    for (int j = t; j < 800; j += 256) {
        float s = 0.f;
        #pragma unroll
        for (int kk = 0; kk < 8; ++kk) s += part[kk*800 + j];
        resb[j] = s;
    }
    __syncthreads();
    for (int o = t; o < 768; o += 256) {
        int r = o >> 5, c2 = o & 31;
        int col = bid*32 + c2;
        if (col >= N_CLS) continue;
        float dot = resb[c2*25 + r];
        float invk = rsqrtf(resb[c2*25 + 24]);
        float cosv = fminf(fmaxf(dot * inv_s[r] * invk, -1.f), 1.f);
        float oc = cosv * S_SCALE;
        float af = oc;
        if (lab_s[r] == col) {
            float tl = cosv;
            float sint = sqrtf(fmaxf(1.f - tl*tl, 0.f));
            float ctm = tl*COS_M - sint*SIN_M;
            float ftl = (tl > TH_C) ? ctm : (tl - MM_C);
            af = ftl * S_SCALE;
        }
        out[r*N_CLS + col] = af;
        out[240001 + r*N_CLS + col] = oc;
    }
}

extern "C" void kernel_launch(void* const* d_in, const int* in_sizes, int n_in,
                              void* d_out, int out_size, void* d_ws, size_t ws_size,
                              hipStream_t stream) {
    (void)in_sizes; (void)n_in; (void)out_size;
    const float* emb  = (const float*)d_in[0];
    const float* conv = (const float*)d_in[1];
    const float* kern = (const float*)d_in[2];
    const int*   lab  = (const int*)d_in[3];
    float* out = (float*)d_out;
    float* ws  = (float*)d_ws;
    float* dists = ws;                 // 576 floats
    float* Dmat  = ws + 576;           // 576 floats
    float* rm_ws = ws + 1152;          // 276*256 = 70656 floats
    unsigned short* E16 = (unsigned short*)(ws + 71808);  // 276*65536 ushorts = 36.2 MB

    const size_t ws_needed = (size_t)71808*4 + (size_t)276*65536*2;
    if (ws_size >= ws_needed) {
        k_gemmE<<<624, 512, 0, stream>>>(emb, conv, dists, Dmat, rm_ws, E16);
        k_sink<<<276, 512, 0, stream>>>(E16, rm_ws, Dmat);
    } else {
        k_pairs_all<<<312, 1024, 0, stream>>>(emb, conv, dists, Dmat);
    }
    k_arc_fin<<<314, 256, 0, stream>>>(emb, kern, lab, dists, Dmat, out);
}